// Round 1
// baseline (121.693 us; speedup 1.0000x reference)
//
#include <hip/hip_runtime.h>

// Bilinear table interpolation, TF _interpolate_bilinear semantics:
//   fl = clip(floor(q), 0, size-2); alpha = clip(q - fl, 0, 1)
// inputs[N][2] = (x, v); qy over H rows from x, qx over W cols from v.
// 4 points per thread: float4 in-loads, 16 batched random gathers, float4 store.

#ifndef GRID_H
#define GRID_H 1024
#define GRID_W 1024
#endif

__global__ __launch_bounds__(256) void tableInterp_kernel(
    const float* __restrict__ in,      // N*2 floats, interleaved (x, v)
    const float* __restrict__ grid,    // H*W floats
    const float* __restrict__ bounds,  // [x_lo, x_hi, v_lo, v_hi]
    float* __restrict__ out,           // N floats
    int n_pts)
{
    const int H = GRID_H, W = GRID_W;
    // bounds are uniform; scalar-cached loads
    const float x_lo = bounds[0];
    const float x_hi = bounds[1];
    const float v_lo = bounds[2];
    const float v_hi = bounds[3];
    const float sy = (float)(H - 1) / (x_hi - x_lo);
    const float sx = (float)(W - 1) / (v_hi - v_lo);

    const int t = blockIdx.x * blockDim.x + threadIdx.x;
    const int base = t * 4;
    if (base >= n_pts) return;

    float xs[4], vs[4], res[4];

    if (base + 3 < n_pts) {
        // fast path: two float4 loads cover points 4t..4t+3
        const float4* in4 = (const float4*)in;
        float4 p01 = in4[2 * t + 0];   // (x0, v0, x1, v1)
        float4 p23 = in4[2 * t + 1];   // (x2, v2, x3, v3)
        xs[0] = p01.x; vs[0] = p01.y;
        xs[1] = p01.z; vs[1] = p01.w;
        xs[2] = p23.x; vs[2] = p23.y;
        xs[3] = p23.z; vs[3] = p23.w;
    } else {
#pragma unroll
        for (int k = 0; k < 4; ++k) {
            int p = base + k < n_pts ? base + k : n_pts - 1;
            xs[k] = in[2 * p + 0];
            vs[k] = in[2 * p + 1];
        }
    }

#pragma unroll
    for (int k = 0; k < 4; ++k) {
        float qy = (xs[k] - x_lo) * sy;
        float qx = (vs[k] - v_lo) * sx;
        float fy = fminf(fmaxf(floorf(qy), 0.0f), (float)(H - 2));
        float fx = fminf(fmaxf(floorf(qx), 0.0f), (float)(W - 2));
        float ay = fminf(fmaxf(qy - fy, 0.0f), 1.0f);
        float ax = fminf(fmaxf(qx - fx, 0.0f), 1.0f);
        int y0 = (int)fy;
        int x0 = (int)fx;
        const float* g = grid + (y0 * W + x0);
        float tl = g[0];
        float tr = g[1];
        float bl = g[W];
        float br = g[W + 1];
        float top = tl + (tr - tl) * ax;
        float bot = bl + (br - bl) * ax;
        res[k] = top + (bot - top) * ay;
    }

    if (base + 3 < n_pts) {
        float4 o;
        o.x = res[0]; o.y = res[1]; o.z = res[2]; o.w = res[3];
        ((float4*)out)[t] = o;
    } else {
#pragma unroll
        for (int k = 0; k < 4; ++k)
            if (base + k < n_pts) out[base + k] = res[k];
    }
}

extern "C" void kernel_launch(void* const* d_in, const int* in_sizes, int n_in,
                              void* d_out, int out_size, void* d_ws, size_t ws_size,
                              hipStream_t stream) {
    const float* in     = (const float*)d_in[0];   // (N, 2) fp32
    const float* grid   = (const float*)d_in[1];   // (H, W) fp32
    const float* bounds = (const float*)d_in[2];   // (2, 2) fp32
    float* out = (float*)d_out;                    // N fp32

    const int n_pts = in_sizes[0] / 2;
    const int n_threads = (n_pts + 3) / 4;
    const int block = 256;
    const int blocks = (n_threads + block - 1) / block;
    tableInterp_kernel<<<blocks, block, 0, stream>>>(in, grid, bounds, out, n_pts);
}